// Round 1
// baseline (281.759 us; speedup 1.0000x reference)
//
#include <hip/hip_runtime.h>
#include <math.h>

#define N_NODES 50000
#define N_EDGES 800000
#define IN_C 16
#define HID_C 16
#define OUT_C 10
#define N_GRAPHS 500
#define EDGE_DIM 3
#define MLP_HID 25
#define BN_EPS 1e-5f

#define SCAN_NB ((N_NODES + 255) / 256)   // 196 blocks
#define NZB 200                           // zero-phase blocks in setup
#define ZERO_F4 412500                    // (AGG1+AGG2+CNT) = 1,650,000 dwords

typedef __attribute__((ext_vector_type(8))) _Float16 half8;
typedef __attribute__((ext_vector_type(2))) _Float16 half2v;
typedef __attribute__((ext_vector_type(4))) float f32x4;
union U4H8 { uint4 u; half8 h; half2v p[4]; };
union HU { _Float16 h; unsigned short u; };

// ---------------- setup: W-pack(f16) + BN-fold + goff + zero AGG/CNT --------

// blk 0..6  : pack W' fragments (as before)
// blk 7..8  : BN-fold AC + goff binary search
// blk 9..208: grid-stride zero of [AGG1|AGG2|CNT] (contiguous, 412500 f32x4);
//             blk 9/t0 zeroes the scan ticket
__global__ __launch_bounds__(256) void setup_kernel(
    const float* __restrict__ W1a, const float* __restrict__ b1a,
    const float* __restrict__ g1, const float* __restrict__ bt1,
    const float* __restrict__ m1, const float* __restrict__ v1,
    const float* __restrict__ W2a, const float* __restrict__ b2a,
    const float* __restrict__ g2, const float* __restrict__ bt2,
    const float* __restrict__ m2, const float* __restrict__ v2,
    const float* __restrict__ W1b, const float* __restrict__ b1b,
    const float* __restrict__ W2b, const float* __restrict__ b2b,
    const int* __restrict__ batch,
    float* __restrict__ AC1, float* __restrict__ AC2,
    unsigned int* __restrict__ WF1, unsigned int* __restrict__ WF2,
    int* __restrict__ goff, float* __restrict__ zbase, int* __restrict__ ticket)
{
    const int blk = blockIdx.x;
    const int tid = threadIdx.x;
    if (blk < 7) {
        int t = blk * 256 + tid;
        if (t >= 1664) return;
        const float *Wb, *bb; unsigned int *WH;
        int tl = t;
        if (t < 832) { Wb = W1b; bb = b1b; WH = WF1; }
        else { tl = t - 832; Wb = W2b; bb = b2b; WH = WF2; }
        int m = tl >> 6;
        int L = tl & 63;
        int q = L >> 4, o = L & 15;
        unsigned int hi[8];
        for (int j = 0; j < 8; ++j) {
            int kp = m*32 + q*8 + j;          // 0..415
            int k = kp >> 4, i = kp & 15;
            float w = (k < 25) ? Wb[k*256 + i*16 + o] : bb[i*16 + o];
            HU cv; cv.h = (_Float16)w;        // f16 RNE
            hi[j] = cv.u;
        }
        int base = (m*64 + L) * 4;
        for (int d = 0; d < 4; ++d)
            WH[base + d] = hi[2*d] | (hi[2*d+1] << 16);
        return;
    }
    if (blk == 7 || blk == 8) {
        if (blk == 7) {
            if (tid < 26) {
                int k = tid;
                if (k < 25) {
                    float sc = g1[k] / sqrtf(v1[k] + BN_EPS);
                    AC1[k*4+0] = sc * W1a[0*MLP_HID+k];
                    AC1[k*4+1] = sc * W1a[1*MLP_HID+k];
                    AC1[k*4+2] = sc * W1a[2*MLP_HID+k];
                    AC1[k*4+3] = sc * (b1a[k] - m1[k]) + bt1[k];
                } else {
                    AC1[100] = 0.f; AC1[101] = 0.f; AC1[102] = 0.f; AC1[103] = 1.f;
                }
            } else if (tid >= 32 && tid < 58) {
                int k = tid - 32;
                if (k < 25) {
                    float sc = g2[k] / sqrtf(v2[k] + BN_EPS);
                    AC2[k*4+0] = sc * W2a[0*MLP_HID+k];
                    AC2[k*4+1] = sc * W2a[1*MLP_HID+k];
                    AC2[k*4+2] = sc * W2a[2*MLP_HID+k];
                    AC2[k*4+3] = sc * (b2a[k] - m2[k]) + bt2[k];
                } else {
                    AC2[100] = 0.f; AC2[101] = 0.f; AC2[102] = 0.f; AC2[103] = 1.f;
                }
            }
        }
        int g = (blk - 7) * 256 + tid;
        if (g <= N_GRAPHS) {
            int lo = 0, hi = N_NODES;
            while (lo < hi) {
                int mid = (lo + hi) >> 1;
                if (batch[mid] < g) lo = mid + 1; else hi = mid;
            }
            goff[g] = lo;
        }
        return;
    }
    // zero phase: AGG1 | AGG2 | CNT contiguous, 16B-aligned
    int z = (blk - 9) * 256 + tid;
    f32x4* Z = (f32x4*)zbase;
    const f32x4 zero4 = {0.f, 0.f, 0.f, 0.f};
    for (int i = z; i < ZERO_F4; i += NZB * 256) Z[i] = zero4;
    if (blk == 9 && tid == 0) *ticket = 0;
}

// ---------------- CSR build ----------------

__global__ __launch_bounds__(256) void rank_kernel(const int* __restrict__ dst,
                                                   int* __restrict__ cnt,
                                                   int* __restrict__ rank) {
    int e = blockIdx.x * blockDim.x + threadIdx.x;
    if (e < N_EDGES) rank[e] = atomicAdd(&cnt[dst[e]], 1);
}

// phase 1 (+fused phase 2 in the last-arriving block via device-scope ticket)
__global__ __launch_bounds__(256) void scan_p1(const int* __restrict__ cnt,
                                               int* __restrict__ bsum,
                                               int* __restrict__ bpre,
                                               int* __restrict__ off,
                                               int* __restrict__ ticket) {
    __shared__ int lds[256];
    __shared__ int sDone;
    int t = threadIdx.x;
    int idx = blockIdx.x * 256 + t;
    lds[t] = (idx < N_NODES) ? cnt[idx] : 0;
    __syncthreads();
    for (int d = 128; d > 0; d >>= 1) {
        if (t < d) lds[t] += lds[t + d];
        __syncthreads();
    }
    if (t == 0) {
        bsum[blockIdx.x] = lds[0];
        __threadfence();
        sDone = atomicAdd(ticket, 1);
    }
    __syncthreads();
    if (sDone != SCAN_NB - 1) return;
    __threadfence();
    int v = (t < SCAN_NB) ? bsum[t] : 0;
    __syncthreads();
    lds[t] = v;
    __syncthreads();
    for (int d = 1; d < 256; d <<= 1) {
        int u = (t >= d) ? lds[t - d] : 0;
        __syncthreads();
        lds[t] += u;
        __syncthreads();
    }
    if (t < SCAN_NB) bpre[t] = (t > 0) ? lds[t - 1] : 0;
    if (t == 255) off[N_NODES] = lds[255];
}

__global__ __launch_bounds__(256) void scan_p3(const int* __restrict__ cnt,
                                               const int* __restrict__ bpre,
                                               int* __restrict__ off) {
    __shared__ int lds[256];
    int t = threadIdx.x;
    int idx = blockIdx.x * 256 + t;
    int v = (idx < N_NODES) ? cnt[idx] : 0;
    lds[t] = v;
    __syncthreads();
    for (int d = 1; d < 256; d <<= 1) {
        int u = (t >= d) ? lds[t - d] : 0;
        __syncthreads();
        lds[t] += u;
        __syncthreads();
    }
    if (idx < N_NODES) off[idx] = bpre[blockIdx.x] + lds[t] - v;
}

// Permute edge data into CSR-slot order so the edge kernel walks edges
// sorted by destination (coalesced reads, segmented in-register reduce).
// Reads coalesced; scattered writes land in L2 (ssrc/ddst 3.2MB each) /
// stream out once (ea4 12.8MB). One-time cost, enables deleting the
// 51.2MB msg write + 51.2MB msg read per layer.
__global__ __launch_bounds__(256) void permute_kernel(
    const int* __restrict__ src, const int* __restrict__ dst,
    const int* __restrict__ rank, const int* __restrict__ off,
    const float* __restrict__ eattr,
    int* __restrict__ ssrc, int* __restrict__ ddst, float4* __restrict__ ea4)
{
    int e = blockIdx.x * blockDim.x + threadIdx.x;
    int d = dst[e];
    int p = off[d] + rank[e];
    ssrc[p] = src[e];
    ddst[p] = d;
    float4 a;
    a.x = eattr[(size_t)e*3+0];
    a.y = eattr[(size_t)e*3+1];
    a.z = eattr[(size_t)e*3+2];
    a.w = 0.f;
    ea4[p] = a;
}

// ---------------- hot path: fused f16 MFMA edge kernel, CSR order ----------

// Per wave: 64 CSR-consecutive edges = 4 tiles of 16 (dst keys sorted).
// Same MFMA core as before (swapped operands: lane (q,el) holds
// msg[edge el][o=q*4..+3]). Epilogue replaced: instead of 4 scattered
// dwordx4 stores to msg_buf, a 16-lane segmented inclusive scan over el
// (keys = ddst, sorted within the tile) reduces runs in-register; only
// segment-end lanes (avg ~2/tile) atomically add their f32x4 into the
// 3.2MB L2-resident AGG[n][16]. Partial segments at tile/wave boundaries
// compose via the atomics. Deletes node_gather's 51.2MB read entirely.
__global__ __launch_bounds__(256) void edge_fused_kernel(
    const float* __restrict__ xin,
    const int* __restrict__ ssrc,
    const int* __restrict__ ddst,
    const float4* __restrict__ ea4,
    const float* __restrict__ AC,
    const unsigned int* __restrict__ WF,
    float* __restrict__ AGG)
{
    __shared__ uint4 wf_s[832];                         // 13312 B
    const int tid = threadIdx.x;
    #pragma unroll
    for (int it = 0; it < 4; ++it) {
        int gi = tid + it*256;
        if (gi < 832) wf_s[gi] = ((const uint4*)WF)[gi];
    }
    __syncthreads();

    const int wave = tid >> 6;
    const int lane = tid & 63;
    const int q    = lane >> 4;
    const int el   = lane & 15;
    const int i0   = (q & 1) * 8;
    const bool bsel = (q >> 1) != 0;
    const int P0   = (blockIdx.x * 4 + wave) * 64;      // CSR slot base

    // coalesced scalar plane: lane L <-> slot P0+L
    const int sAll = ssrc[P0 + lane];
    const int nAll = ddst[P0 + lane];

    // per-tile src via shuffle; eattr as one float4 per (t,el)
    int   sT[4];
    float a0[4], a1[4], a2[4];
    #pragma unroll
    for (int t = 0; t < 4; ++t) {
        sT[t] = __shfl(sAll, t*16 + el);
        float4 at = ea4[P0 + t*16 + el];
        a0[t] = at.x; a1[t] = at.y; a2[t] = at.z;
    }

    // xs gather + f16 RNE once per tile
    U4H8 xf[4];
    #pragma unroll
    for (int t = 0; t < 4; ++t) {
        const float4* xp = (const float4*)(xin + (size_t)sT[t]*16 + i0);
        const float4 xl = xp[0], xh = xp[1];
        const float x8[8] = {xl.x,xl.y,xl.z,xl.w,xh.x,xh.y,xh.z,xh.w};
        #pragma unroll
        for (int j = 0; j < 4; ++j) {
            half2v tv; tv.x = (_Float16)x8[2*j]; tv.y = (_Float16)x8[2*j+1];
            xf[t].p[j] = tv;
        }
    }

    f32x4 acc0 = {0.f,0.f,0.f,0.f}, acc1 = {0.f,0.f,0.f,0.f};
    f32x4 acc2 = {0.f,0.f,0.f,0.f}, acc3 = {0.f,0.f,0.f,0.f};
    #pragma unroll 1
    for (int m = 0; m < 13; ++m) {
        const float4 Ae = *(const float4*)(AC + m*8);
        const float4 Ao = *(const float4*)(AC + m*8 + 4);
        const float A0 = bsel ? Ao.x : Ae.x;
        const float A1 = bsel ? Ao.y : Ae.y;
        const float A2 = bsel ? Ao.z : Ae.z;
        const float A3 = bsel ? Ao.w : Ae.w;
        U4H8 w; w.u = wf_s[m*64 + lane];     // ds_read_b128 (LDS pipe)
        #pragma unroll
        for (int t = 0; t < 4; ++t) {
            float h = fmaxf(fmaf(a2[t], A2, fmaf(a1[t], A1,
                              fmaf(a0[t], A0, A3))), 0.f);
            _Float16 hh = (_Float16)h;
            half2v h2; h2.x = hh; h2.y = hh;
            U4H8 f;
            #pragma unroll
            for (int j = 0; j < 4; ++j) f.p[j] = h2 * xf[t].p[j];
            f32x4 a = (t==0) ? acc0 : (t==1) ? acc1 : (t==2) ? acc2 : acc3;
            a = __builtin_amdgcn_mfma_f32_16x16x32_f16(w.h, f.h, a, 0, 0, 0);
            if (t==0) acc0 = a; else if (t==1) acc1 = a;
            else if (t==2) acc2 = a; else acc3 = a;
        }
    }

    // segmented reduce over el (dst keys sorted) + atomic scatter into AGG
    #pragma unroll
    for (int t = 0; t < 4; ++t) {
        f32x4 a = (t==0) ? acc0 : (t==1) ? acc1 : (t==2) ? acc2 : acc3;
        const int nt = __shfl(nAll, t*16 + el);   // node of my slot
        #pragma unroll
        for (int s = 1; s < 16; s <<= 1) {
            // all lanes active for the shfls; predicate applied after
            float ux = __shfl(a.x, lane - s);
            float uy = __shfl(a.y, lane - s);
            float uz = __shfl(a.z, lane - s);
            float uw = __shfl(a.w, lane - s);
            int   ku = __shfl(nt,  lane - s);
            if (el >= s && ku == nt) {
                a.x += ux; a.y += uy; a.z += uz; a.w += uw;
            }
        }
        int nn = __shfl(nAll, t*16 + el + 1);     // next slot's node (garbage at el==15,t==3; masked)
        if (el == 15 || nn != nt) {               // segment end within tile
            float* p = AGG + (size_t)nt * HID_C + q*4;
            unsafeAtomicAdd(p+0, a.x);
            unsafeAtomicAdd(p+1, a.y);
            unsafeAtomicAdd(p+2, a.z);
            unsafeAtomicAdd(p+3, a.w);
        }
    }
}

// finalize: mean (deg from cnt) + x@root + bias + ELU. 16 threads/node.
__global__ __launch_bounds__(256) void node_finalize_kernel(
    const float* __restrict__ xin, const float* __restrict__ AGG,
    const int* __restrict__ cnt,
    const float* __restrict__ root, const float* __restrict__ bias,
    float* __restrict__ xout)
{
    int t = blockIdx.x * blockDim.x + threadIdx.x;
    int n = t >> 4;
    int o = t & 15;
    if (n >= N_NODES) return;
    float inv = 1.f / fmaxf((float)cnt[n], 1.f);
    float acc = fmaf(AGG[t], inv, bias[o]);
    const float* xr = xin + (size_t)n * IN_C;
    #pragma unroll
    for (int i = 0; i < IN_C; ++i)
        acc = fmaf(xr[i], root[i*HID_C+o], acc);
    xout[t] = acc > 0.f ? acc : (expf(acc) - 1.f);
}

// fused: global mean pool (batch sorted -> contiguous segments) + final linear
__global__ __launch_bounds__(64) void pool_final_kernel(
    const float* __restrict__ xin, const int* __restrict__ goff,
    const float* __restrict__ fcW, const float* __restrict__ fcb,
    float* __restrict__ out)
{
    __shared__ float part[4][HID_C];
    __shared__ float pooled[HID_C];
    int g = blockIdx.x;
    int t = threadIdx.x;
    int c = t & 15, sub = t >> 4;
    int lo = goff[g], hi = goff[g+1];
    float s = 0.f;
    for (int n = lo + sub; n < hi; n += 4)
        s += xin[(size_t)n*HID_C + c];
    part[sub][c] = s;
    __syncthreads();
    if (t < HID_C) {
        pooled[t] = (part[0][t] + part[1][t] + part[2][t] + part[3][t])
                    / fmaxf((float)(hi - lo), 1.f);
    }
    __syncthreads();
    if (t < OUT_C) {
        float acc = fcb[t];
        #pragma unroll
        for (int i = 0; i < HID_C; ++i)
            acc = fmaf(pooled[i], fcW[i*OUT_C+t], acc);
        out[g*OUT_C + t] = acc;
    }
}

// ---------------- launch ----------------

extern "C" void kernel_launch(void* const* d_in, const int* in_sizes, int n_in,
                              void* d_out, int out_size, void* d_ws, size_t ws_size,
                              hipStream_t stream)
{
    const float* x     = (const float*)d_in[0];
    const int*   ei    = (const int*)d_in[1];
    const float* eattr = (const float*)d_in[2];
    const int*   batch = (const int*)d_in[3];
    const float* W1a   = (const float*)d_in[4];
    const float* b1a   = (const float*)d_in[5];
    const float* g1    = (const float*)d_in[6];
    const float* bt1   = (const float*)d_in[7];
    const float* m1    = (const float*)d_in[8];
    const float* v1    = (const float*)d_in[9];
    const float* W1b   = (const float*)d_in[10];
    const float* b1b   = (const float*)d_in[11];
    const float* root1 = (const float*)d_in[12];
    const float* bias1 = (const float*)d_in[13];
    const float* W2a   = (const float*)d_in[14];
    const float* b2a   = (const float*)d_in[15];
    const float* g2    = (const float*)d_in[16];
    const float* bt2   = (const float*)d_in[17];
    const float* m2    = (const float*)d_in[18];
    const float* v2    = (const float*)d_in[19];
    const float* W2b   = (const float*)d_in[20];
    const float* b2b   = (const float*)d_in[21];
    const float* root2 = (const float*)d_in[22];
    const float* bias2 = (const float*)d_in[23];
    const float* fcW   = (const float*)d_in[24];
    const float* fcb   = (const float*)d_in[25];

    const int* src = ei;
    const int* dst = ei + N_EDGES;

    float* ws   = (float*)d_ws;
    int*   SSRC = (int*)(ws + 0);                       //   800,000 i
    int*   DDST = (int*)(ws + 800000);                  //   800,000 i
    float* EA4  = ws + 1600000;                         // 3,200,000 f (16B aligned)
    float* AGG1 = ws + 4800000;                         //   800,000 f } zeroed
    float* AGG2 = ws + 5600000;                         //   800,000 f } together
    int*   CNT  = (int*)(ws + 6400000);                 //    50,000 i } in setup
    int*   RANK = (int*)(ws + 6450000);                 //   800,000 i
    int*   OFF  = (int*)(ws + 7250000);                 //    50,001 i (+pad)
    int*   GOFF = (int*)(ws + 7300064);                 //       501 i (+pad)
    unsigned int* WF1 = (unsigned int*)(ws + 7300576);  //     3,328 u (16B aligned)
    unsigned int* WF2 = (unsigned int*)(ws + 7303904);  //     3,328 u
    float* AC1  = ws + 7307232;                         //       104 f (+pad)
    float* AC2  = ws + 7307344;                         //       104 f (+pad)
    int*   BSUM = (int*)(ws + 7307456);                 //       196 i (+pad)
    int*   BPRE = (int*)(ws + 7307712);                 //       196 i (+pad)
    int*   TICK = (int*)(ws + 7307968);                 //         1 i
    float* X1   = ws + 7308032;                         //   800,000 f
    float* X2   = ws + 8108032;                         //   800,000 f
    // total ~8,908,032 f = 35.6 MB

    setup_kernel<<<9 + NZB, 256, 0, stream>>>(
        W1a, b1a, g1, bt1, m1, v1, W2a, b2a, g2, bt2, m2, v2,
        W1b, b1b, W2b, b2b, batch, AC1, AC2, WF1, WF2, GOFF, AGG1, TICK);
    rank_kernel<<<N_EDGES/256, 256, 0, stream>>>(dst, CNT, RANK);
    scan_p1<<<SCAN_NB, 256, 0, stream>>>(CNT, BSUM, BPRE, OFF, TICK);
    scan_p3<<<SCAN_NB, 256, 0, stream>>>(CNT, BPRE, OFF);
    permute_kernel<<<N_EDGES/256, 256, 0, stream>>>(src, dst, RANK, OFF, eattr,
                                                    SSRC, DDST, (float4*)EA4);

    edge_fused_kernel<<<N_EDGES/256, 256, 0, stream>>>(x, SSRC, DDST,
                                                       (const float4*)EA4,
                                                       AC1, WF1, AGG1);
    node_finalize_kernel<<<(N_NODES*16)/256, 256, 0, stream>>>(x, AGG1, CNT,
                                                               root1, bias1, X1);

    edge_fused_kernel<<<N_EDGES/256, 256, 0, stream>>>(X1, SSRC, DDST,
                                                       (const float4*)EA4,
                                                       AC2, WF2, AGG2);
    node_finalize_kernel<<<(N_NODES*16)/256, 256, 0, stream>>>(X1, AGG2, CNT,
                                                               root2, bias2, X2);

    pool_final_kernel<<<N_GRAPHS, 64, 0, stream>>>(X2, GOFF, fcW, fcb, (float*)d_out);
}

// Round 2
// 251.443 us; speedup vs baseline: 1.1206x; 1.1206x over previous
//
#include <hip/hip_runtime.h>
#include <math.h>

#define N_NODES 50000
#define N_EDGES 800000
#define IN_C 16
#define HID_C 16
#define OUT_C 10
#define N_GRAPHS 500
#define EDGE_DIM 3
#define MLP_HID 25
#define BN_EPS 1e-5f

#define SCAN_NB ((N_NODES + 255) / 256)   // 196 blocks
#define NZB 200                           // repack/zero blocks in setup

typedef __attribute__((ext_vector_type(8))) _Float16 half8;
typedef __attribute__((ext_vector_type(2))) _Float16 half2v;
typedef __attribute__((ext_vector_type(4))) float f32x4;
union U4H8 { uint4 u; half8 h; half2v p[4]; };
union HU { _Float16 h; unsigned short u; };

// ---------------- setup: W-pack(f16) + BN-fold + goff + repack + zero -------

// blk 0..6  : pack W' = [Wb rows ; bb rows] (416x16) into per-MFMA per-lane
//             f16 fragments (RNE), as before.
// blk 7..8  : fold BN into AC; goff[g] = lower_bound(batch, g)
// blk 9..208: grid-stride: zero CNT, repack eattr (3f stride-12) -> EA4
//             (float4 stride-16, edge order), convert x -> XH0 (f16 pairs).
//             blk 9/t0 zeroes the scan ticket.
__global__ __launch_bounds__(256) void setup_kernel(
    const float* __restrict__ W1a, const float* __restrict__ b1a,
    const float* __restrict__ g1, const float* __restrict__ bt1,
    const float* __restrict__ m1, const float* __restrict__ v1,
    const float* __restrict__ W2a, const float* __restrict__ b2a,
    const float* __restrict__ g2, const float* __restrict__ bt2,
    const float* __restrict__ m2, const float* __restrict__ v2,
    const float* __restrict__ W1b, const float* __restrict__ b1b,
    const float* __restrict__ W2b, const float* __restrict__ b2b,
    const int* __restrict__ batch,
    const float* __restrict__ xin, const float* __restrict__ eattr,
    float* __restrict__ AC1, float* __restrict__ AC2,
    unsigned int* __restrict__ WF1, unsigned int* __restrict__ WF2,
    int* __restrict__ goff, int* __restrict__ cnt,
    float4* __restrict__ ea4, unsigned int* __restrict__ xh0,
    int* __restrict__ ticket)
{
    const int blk = blockIdx.x;
    const int tid = threadIdx.x;
    if (blk < 7) {
        int t = blk * 256 + tid;
        if (t >= 1664) return;
        const float *Wb, *bb; unsigned int *WH;
        int tl = t;
        if (t < 832) { Wb = W1b; bb = b1b; WH = WF1; }
        else { tl = t - 832; Wb = W2b; bb = b2b; WH = WF2; }
        int m = tl >> 6;
        int L = tl & 63;
        int q = L >> 4, o = L & 15;
        unsigned int hi[8];
        for (int j = 0; j < 8; ++j) {
            int kp = m*32 + q*8 + j;          // 0..415
            int k = kp >> 4, i = kp & 15;
            float w = (k < 25) ? Wb[k*256 + i*16 + o] : bb[i*16 + o];
            HU cv; cv.h = (_Float16)w;        // f16 RNE
            hi[j] = cv.u;
        }
        int base = (m*64 + L) * 4;
        for (int d = 0; d < 4; ++d)
            WH[base + d] = hi[2*d] | (hi[2*d+1] << 16);
        return;
    }
    if (blk == 7 || blk == 8) {
        if (blk == 7) {
            if (tid < 26) {
                int k = tid;
                if (k < 25) {
                    float sc = g1[k] / sqrtf(v1[k] + BN_EPS);
                    AC1[k*4+0] = sc * W1a[0*MLP_HID+k];
                    AC1[k*4+1] = sc * W1a[1*MLP_HID+k];
                    AC1[k*4+2] = sc * W1a[2*MLP_HID+k];
                    AC1[k*4+3] = sc * (b1a[k] - m1[k]) + bt1[k];
                } else {
                    AC1[100] = 0.f; AC1[101] = 0.f; AC1[102] = 0.f; AC1[103] = 1.f;
                }
            } else if (tid >= 32 && tid < 58) {
                int k = tid - 32;
                if (k < 25) {
                    float sc = g2[k] / sqrtf(v2[k] + BN_EPS);
                    AC2[k*4+0] = sc * W2a[0*MLP_HID+k];
                    AC2[k*4+1] = sc * W2a[1*MLP_HID+k];
                    AC2[k*4+2] = sc * W2a[2*MLP_HID+k];
                    AC2[k*4+3] = sc * (b2a[k] - m2[k]) + bt2[k];
                } else {
                    AC2[100] = 0.f; AC2[101] = 0.f; AC2[102] = 0.f; AC2[103] = 1.f;
                }
            }
        }
        int g = (blk - 7) * 256 + tid;
        if (g <= N_GRAPHS) {
            int lo = 0, hi = N_NODES;
            while (lo < hi) {
                int mid = (lo + hi) >> 1;
                if (batch[mid] < g) lo = mid + 1; else hi = mid;
            }
            goff[g] = lo;
        }
        return;
    }
    // repack/zero phase
    const int bt = (blk - 9) * 256 + tid;
    const int STR = NZB * 256;                 // 51200
    int4* c4 = (int4*)cnt;                     // 50,000 ints = 12,500 int4
    const int4 z4 = {0, 0, 0, 0};
    for (int i = bt; i < 12500; i += STR) c4[i] = z4;
    for (int e = bt; e < N_EDGES; e += STR) {
        float4 a;
        a.x = eattr[e*3+0];
        a.y = eattr[e*3+1];
        a.z = eattr[e*3+2];
        a.w = 0.f;
        ea4[e] = a;
    }
    const float2* x2 = (const float2*)xin;     // 400,000 f32 pairs
    for (int i = bt; i < 400000; i += STR) {
        float2 v = x2[i];
        HU h0; h0.h = (_Float16)v.x;
        HU h1; h1.h = (_Float16)v.y;
        xh0[i] = (unsigned int)h0.u | ((unsigned int)h1.u << 16);
    }
    if (blk == 9 && tid == 0) *ticket = 0;
}

// ---------------- CSR build ----------------

__global__ __launch_bounds__(256) void rank_kernel(const int* __restrict__ dst,
                                                   int* __restrict__ cnt,
                                                   int* __restrict__ rank) {
    int e = blockIdx.x * blockDim.x + threadIdx.x;
    if (e < N_EDGES) rank[e] = atomicAdd(&cnt[dst[e]], 1);
}

// phase 1 (+fused phase 2 in the last-arriving block via device-scope ticket)
__global__ __launch_bounds__(256) void scan_p1(const int* __restrict__ cnt,
                                               int* __restrict__ bsum,
                                               int* __restrict__ bpre,
                                               int* __restrict__ off,
                                               int* __restrict__ ticket) {
    __shared__ int lds[256];
    __shared__ int sDone;
    int t = threadIdx.x;
    int idx = blockIdx.x * 256 + t;
    lds[t] = (idx < N_NODES) ? cnt[idx] : 0;
    __syncthreads();
    for (int d = 128; d > 0; d >>= 1) {
        if (t < d) lds[t] += lds[t + d];
        __syncthreads();
    }
    if (t == 0) {
        bsum[blockIdx.x] = lds[0];
        __threadfence();
        sDone = atomicAdd(ticket, 1);
    }
    __syncthreads();
    if (sDone != SCAN_NB - 1) return;
    __threadfence();
    int v = (t < SCAN_NB) ? bsum[t] : 0;
    __syncthreads();
    lds[t] = v;
    __syncthreads();
    for (int d = 1; d < 256; d <<= 1) {
        int u = (t >= d) ? lds[t - d] : 0;
        __syncthreads();
        lds[t] += u;
        __syncthreads();
    }
    if (t < SCAN_NB) bpre[t] = (t > 0) ? lds[t - 1] : 0;
    if (t == 255) off[N_NODES] = lds[255];
}

__global__ __launch_bounds__(256) void scan_p3(const int* __restrict__ cnt,
                                               const int* __restrict__ bpre,
                                               int* __restrict__ off) {
    __shared__ int lds[256];
    int t = threadIdx.x;
    int idx = blockIdx.x * 256 + t;
    int v = (idx < N_NODES) ? cnt[idx] : 0;
    lds[t] = v;
    __syncthreads();
    for (int d = 1; d < 256; d <<= 1) {
        int u = (t >= d) ? lds[t - d] : 0;
        __syncthreads();
        lds[t] += u;
        __syncthreads();
    }
    if (idx < N_NODES) off[idx] = bpre[blockIdx.x] + lds[t] - v;
}

// ---------------- hot path: f16 MFMA edge kernel, 4 tiles/wave --------------

// VMEM diet v7 (per wave of 64 edges, ~16 VMEM instrs, was ~31):
//  - src/dst/rank coalesced dwords (3) + off gather (1)
//  - eattr via pre-packed EA4 float4 (4, was 12 scalar dwords)
//  - x gathered as pre-converted f16 rows from XH (4 dwordx4, was 8; also
//    deletes the per-tile cvt chain -> less VALU)
//  - msg store 1 dwordx4 per tile (4)
// WF fragments staged in LDS once per block; MFMA operands swapped so lane
// (q,el) holds msg[edge el][o=q*4..+3] (one contiguous store per tile).
__global__ __launch_bounds__(256) void edge_mfma7_kernel(
    const unsigned short* __restrict__ xh,
    const int* __restrict__ src,
    const int* __restrict__ dst,
    const int* __restrict__ rank,
    const int* __restrict__ off,
    const float4* __restrict__ ea4,
    const float* __restrict__ AC,
    const unsigned int* __restrict__ WF,
    float* __restrict__ msg_buf)
{
    __shared__ uint4 wf_s[832];                         // 13312 B
    const int tid = threadIdx.x;
    #pragma unroll
    for (int it = 0; it < 4; ++it) {
        int gi = tid + it*256;
        if (gi < 832) wf_s[gi] = ((const uint4*)WF)[gi];
    }
    __syncthreads();

    const int wave = tid >> 6;
    const int lane = tid & 63;
    const int q    = lane >> 4;
    const int el   = lane & 15;
    const int i0   = (q & 1) * 8;
    const bool bsel = (q >> 1) != 0;
    const int E0   = (blockIdx.x * 4 + wave) * 64;

    // coalesced scalar plane: lane L <-> edge E0+L
    const int sAll = src[E0 + lane];
    const int dAll = dst[E0 + lane];
    const int rAll = rank[E0 + lane];
    const int pAll = off[dAll] + rAll;     // CSR slot of edge E0+lane

    // per-tile src via shuffle; eattr as one float4 per (t,el)
    int   sT[4];
    float a0[4], a1[4], a2[4];
    #pragma unroll
    for (int t = 0; t < 4; ++t) {
        sT[t] = __shfl(sAll, t*16 + el);
        float4 at = ea4[E0 + t*16 + el];
        a0[t] = at.x; a1[t] = at.y; a2[t] = at.z;
    }

    // x gather: one dwordx4 of pre-converted f16 per tile
    U4H8 xf[4];
    #pragma unroll
    for (int t = 0; t < 4; ++t)
        xf[t].u = *(const uint4*)(const void*)(xh + (size_t)sT[t]*16 + i0);

    f32x4 acc0 = {0.f,0.f,0.f,0.f}, acc1 = {0.f,0.f,0.f,0.f};
    f32x4 acc2 = {0.f,0.f,0.f,0.f}, acc3 = {0.f,0.f,0.f,0.f};
    #pragma unroll 1
    for (int m = 0; m < 13; ++m) {
        // wave-uniform s_load of AC rows 2m, 2m+1; per-lane parity select
        const float4 Ae = *(const float4*)(AC + m*8);
        const float4 Ao = *(const float4*)(AC + m*8 + 4);
        const float A0 = bsel ? Ao.x : Ae.x;
        const float A1 = bsel ? Ao.y : Ae.y;
        const float A2 = bsel ? Ao.z : Ae.z;
        const float A3 = bsel ? Ao.w : Ae.w;
        U4H8 w; w.u = wf_s[m*64 + lane];     // ds_read_b128 (LDS pipe)
        #pragma unroll
        for (int t = 0; t < 4; ++t) {
            float h = fmaxf(fmaf(a2[t], A2, fmaf(a1[t], A1,
                              fmaf(a0[t], A0, A3))), 0.f);
            _Float16 hh = (_Float16)h;
            half2v h2; h2.x = hh; h2.y = hh;
            U4H8 f;
            #pragma unroll
            for (int j = 0; j < 4; ++j) f.p[j] = h2 * xf[t].p[j];
            // swapped operands: D = W'^T @ H^T = msg^T
            f32x4 a = (t==0) ? acc0 : (t==1) ? acc1 : (t==2) ? acc2 : acc3;
            a = __builtin_amdgcn_mfma_f32_16x16x32_f16(w.h, f.h, a, 0, 0, 0);
            if (t==0) acc0 = a; else if (t==1) acc1 = a;
            else if (t==2) acc2 = a; else acc3 = a;
        }
    }

    // lane (q,el) holds msg[edge el][o=q*4..q*4+3] -> one dwordx4 per tile
    #pragma unroll
    for (int t = 0; t < 4; ++t) {
        int row = __shfl(pAll, t*16 + el);
        f32x4 a = (t==0) ? acc0 : (t==1) ? acc1 : (t==2) ? acc2 : acc3;
        *(f32x4*)(msg_buf + (size_t)row * HID_C + q*4) = a;
    }
}

// 4 threads per node (lane = 4-channel group). Segment-sum msg_buf rows
// [off[n], off[n+1]) as f32x4 (1KB per wave-instr, 16 nodes/wave) -> mean
// -> + x@root (root staged in LDS) + bias -> ELU. Optionally emits the f16
// copy of xout for the next layer's edge gather (bit-identical RNE).
__global__ __launch_bounds__(256) void node_gather_kernel(
    const float* __restrict__ xin, const float* __restrict__ msg_buf,
    const int* __restrict__ off,
    const float* __restrict__ root, const float* __restrict__ bias,
    float* __restrict__ xout, unsigned int* __restrict__ xh_out)
{
    __shared__ float root_s[IN_C * HID_C];
    if (threadIdx.x < 64)
        ((float4*)root_s)[threadIdx.x] = ((const float4*)root)[threadIdx.x];
    __syncthreads();

    int t = blockIdx.x * blockDim.x + threadIdx.x;
    int n = t >> 2;
    if (n >= N_NODES) return;
    int c0 = (t & 3) * 4;
    int lo = off[n], hi = off[n+1];
    float inv = 1.f / fmaxf((float)(hi - lo), 1.f);

    const f32x4* m4 = (const f32x4*)msg_buf;
    const int qi = c0 >> 2;
    f32x4 s0 = {0.f,0.f,0.f,0.f}, s1 = {0.f,0.f,0.f,0.f};
    int r = lo;
    for (; r + 2 <= hi; r += 2) {
        s0 += m4[(size_t)r*4 + qi];
        s1 += m4[(size_t)(r+1)*4 + qi];
    }
    if (r < hi) s0 += m4[(size_t)r*4 + qi];
    f32x4 s = s0 + s1;

    const float4 bv = *(const float4*)(bias + c0);
    f32x4 acc;
    acc.x = fmaf(s.x, inv, bv.x);
    acc.y = fmaf(s.y, inv, bv.y);
    acc.z = fmaf(s.z, inv, bv.z);
    acc.w = fmaf(s.w, inv, bv.w);

    const float4* x4 = (const float4*)(xin + (size_t)n * IN_C);
    #pragma unroll
    for (int j = 0; j < 4; ++j) {
        float4 xv = x4[j];
        #pragma unroll
        for (int k = 0; k < 4; ++k) {
            float xi = (k==0) ? xv.x : (k==1) ? xv.y : (k==2) ? xv.z : xv.w;
            const float4 rv = *(const float4*)(root_s + (j*4+k)*HID_C + c0);
            acc.x = fmaf(xi, rv.x, acc.x);
            acc.y = fmaf(xi, rv.y, acc.y);
            acc.z = fmaf(xi, rv.z, acc.z);
            acc.w = fmaf(xi, rv.w, acc.w);
        }
    }

    acc.x = acc.x > 0.f ? acc.x : (expf(acc.x) - 1.f);
    acc.y = acc.y > 0.f ? acc.y : (expf(acc.y) - 1.f);
    acc.z = acc.z > 0.f ? acc.z : (expf(acc.z) - 1.f);
    acc.w = acc.w > 0.f ? acc.w : (expf(acc.w) - 1.f);
    *(f32x4*)(xout + (size_t)n * HID_C + c0) = acc;

    if (xh_out) {
        HU h0, h1, h2, h3;
        h0.h = (_Float16)acc.x; h1.h = (_Float16)acc.y;
        h2.h = (_Float16)acc.z; h3.h = (_Float16)acc.w;
        uint2 pk;
        pk.x = (unsigned int)h0.u | ((unsigned int)h1.u << 16);
        pk.y = (unsigned int)h2.u | ((unsigned int)h3.u << 16);
        ((uint2*)xh_out)[n*4 + qi] = pk;
    }
}

// fused: global mean pool (batch sorted -> contiguous segments) + final linear
__global__ __launch_bounds__(64) void pool_final_kernel(
    const float* __restrict__ xin, const int* __restrict__ goff,
    const float* __restrict__ fcW, const float* __restrict__ fcb,
    float* __restrict__ out)
{
    __shared__ float part[4][HID_C];
    __shared__ float pooled[HID_C];
    int g = blockIdx.x;
    int t = threadIdx.x;
    int c = t & 15, sub = t >> 4;
    int lo = goff[g], hi = goff[g+1];
    float s = 0.f;
    for (int n = lo + sub; n < hi; n += 4)
        s += xin[(size_t)n*HID_C + c];
    part[sub][c] = s;
    __syncthreads();
    if (t < HID_C) {
        pooled[t] = (part[0][t] + part[1][t] + part[2][t] + part[3][t])
                    / fmaxf((float)(hi - lo), 1.f);
    }
    __syncthreads();
    if (t < OUT_C) {
        float acc = fcb[t];
        #pragma unroll
        for (int i = 0; i < HID_C; ++i)
            acc = fmaf(pooled[i], fcW[i*OUT_C+t], acc);
        out[g*OUT_C + t] = acc;
    }
}

// ---------------- launch ----------------

extern "C" void kernel_launch(void* const* d_in, const int* in_sizes, int n_in,
                              void* d_out, int out_size, void* d_ws, size_t ws_size,
                              hipStream_t stream)
{
    const float* x     = (const float*)d_in[0];
    const int*   ei    = (const int*)d_in[1];
    const float* eattr = (const float*)d_in[2];
    const int*   batch = (const int*)d_in[3];
    const float* W1a   = (const float*)d_in[4];
    const float* b1a   = (const float*)d_in[5];
    const float* g1    = (const float*)d_in[6];
    const float* bt1   = (const float*)d_in[7];
    const float* m1    = (const float*)d_in[8];
    const float* v1    = (const float*)d_in[9];
    const float* W1b   = (const float*)d_in[10];
    const float* b1b   = (const float*)d_in[11];
    const float* root1 = (const float*)d_in[12];
    const float* bias1 = (const float*)d_in[13];
    const float* W2a   = (const float*)d_in[14];
    const float* b2a   = (const float*)d_in[15];
    const float* g2    = (const float*)d_in[16];
    const float* bt2   = (const float*)d_in[17];
    const float* m2    = (const float*)d_in[18];
    const float* v2    = (const float*)d_in[19];
    const float* W2b   = (const float*)d_in[20];
    const float* b2b   = (const float*)d_in[21];
    const float* root2 = (const float*)d_in[22];
    const float* bias2 = (const float*)d_in[23];
    const float* fcW   = (const float*)d_in[24];
    const float* fcb   = (const float*)d_in[25];

    const int* src = ei;
    const int* dst = ei + N_EDGES;

    float* ws   = (float*)d_ws;
    float* MSG  = ws;                                   // 12,800,000 f
    float* X1   = ws + 12800000;                        //    800,000 f
    float* X2   = ws + 13600000;                        //    800,000 f
    int*   RANK = (int*)(ws + 14400000);                //    800,000 i
    int*   CNT  = (int*)(ws + 15200000);                //     50,000 i (16B al.)
    int*   OFF  = (int*)(ws + 15250000);                //     50,001 i (+pad)
    int*   GOFF = (int*)(ws + 15300064);                //        501 i (+pad)
    unsigned int* WF1 = (unsigned int*)(ws + 15300576); //      3,328 u
    unsigned int* WF2 = (unsigned int*)(ws + 15303904); //      3,328 u
    float* AC1  = ws + 15307232;                        //        104 f (+pad)
    float* AC2  = ws + 15307344;                        //        104 f (+pad)
    int*   BSUM = (int*)(ws + 15307456);                //        196 i (+pad)
    int*   BPRE = (int*)(ws + 15307712);                //        196 i (+pad)
    int*   TICK = (int*)(ws + 15307968);                //          1 i (+pad)
    float* EA4  = ws + 15308032;                        //  3,200,000 f (16B al.)
    unsigned int* XH0 = (unsigned int*)(ws + 18508032); //    400,000 u (f16 x)
    unsigned int* XH1 = (unsigned int*)(ws + 18908032); //    400,000 u (f16 X1)
    // total ~19,308,032 f = 77.2 MB

    setup_kernel<<<9 + NZB, 256, 0, stream>>>(
        W1a, b1a, g1, bt1, m1, v1, W2a, b2a, g2, bt2, m2, v2,
        W1b, b1b, W2b, b2b, batch, x, eattr,
        AC1, AC2, WF1, WF2, GOFF, CNT, (float4*)EA4, XH0, TICK);
    rank_kernel<<<N_EDGES/256, 256, 0, stream>>>(dst, CNT, RANK);
    scan_p1<<<SCAN_NB, 256, 0, stream>>>(CNT, BSUM, BPRE, OFF, TICK);
    scan_p3<<<SCAN_NB, 256, 0, stream>>>(CNT, BPRE, OFF);

    edge_mfma7_kernel<<<N_EDGES/256, 256, 0, stream>>>(
        (const unsigned short*)XH0, src, dst, RANK, OFF,
        (const float4*)EA4, AC1, WF1, MSG);
    node_gather_kernel<<<(N_NODES*4 + 255)/256, 256, 0, stream>>>(
        x, MSG, OFF, root1, bias1, X1, XH1);

    edge_mfma7_kernel<<<N_EDGES/256, 256, 0, stream>>>(
        (const unsigned short*)XH1, src, dst, RANK, OFF,
        (const float4*)EA4, AC2, WF2, MSG);
    node_gather_kernel<<<(N_NODES*4 + 255)/256, 256, 0, stream>>>(
        X1, MSG, OFF, root2, bias2, X2, (unsigned int*)nullptr);

    pool_final_kernel<<<N_GRAPHS, 64, 0, stream>>>(X2, GOFF, fcW, fcb, (float*)d_out);
}